// Round 4
// baseline (41997.791 us; speedup 1.0000x reference)
//
#include <hip/hip_runtime.h>
#include <math.h>

#define NB 256   // batch
#define NN 256   // code length
#define NK 128   // info bits
#define ND 256   // embedding dim
#define NH 512   // hidden dim

// output layout (floats) in d_out, reference return order: x | f_out | u | p_u
#define OUT_X 0
#define OUT_F 65536
#define OUT_U 131072
#define OUT_P 196608

// ws layout (float units unless noted)
#define E_OFF 0ull
#define E_CNT (255ull * NB * ND)        // 66.8 MB: E levels 1..8, [lvlpos][batch][D]
#define H_OFF (E_OFF + E_CNT)
#define H_CNT (32ull * NB * NH)         // 16 MB hidden chunk buffer [p_local][batch][H]
#define EC_OFF (H_OFF + H_CNT)
#define EC_CNT (2ull * NH)              // embC[bit][H]
#define L_BYTEOFF ((EC_OFF + EC_CNT) * 4ull)  // ints: [batch][256] bit slots

__host__ __device__ __forceinline__ int loff(int d) { return 256 - (1 << (9 - d)); }

// ---------------- GEMM1: hidden = relu(in @ W1 + b1 (+ embC[bit])) ----------------
// rows = CP positions x 256 batches (row = p_local*256 + b), cols = 512.
// grid = (CP*4 row-tiles of 64, 8 col-tiles of 64), 256 threads, 4x4 per thread.
__global__ __launch_bounds__(256, 4) void g1_kernel(
    const float* __restrict__ src,    // level-d base, or null (root: obs2 broadcast)
    float* __restrict__ H,
    const float* __restrict__ W1, const float* __restrict__ b1,
    const float* __restrict__ embC,   // null for cn
    const int* __restrict__ Lbuf, int slotBase,
    const float* __restrict__ obs2, int c0)
{
  __shared__ float As[32][68];
  __shared__ float Ws[32][64];
  const int tid = threadIdx.x;
  const int rt = blockIdx.x;
  const int p_local = rt >> 2;
  const int p = c0 + p_local;
  const int b0 = (rt & 3) << 6;
  const int ct = blockIdx.y << 6;
  const int ty = tid >> 4, tx = tid & 15;
  float acc[4][4] = {{0.f}};
  const float* srcA = src ? src + ((size_t)(2 * p) * NB + b0) * ND : nullptr;
  const float* srcB = src ? src + ((size_t)(2 * p + 1) * NB + b0) * ND : nullptr;

  for (int k0 = 0; k0 < 512; k0 += 32) {
#pragma unroll
    for (int t = 0; t < 8; ++t) {
      const int i = tid + (t << 8);
      const int r = i >> 5, kk = i & 31, k = k0 + kk;
      float v;
      if (!src) v = obs2[k & 255];
      else v = (k < 256) ? srcA[r * ND + k] : srcB[r * ND + (k - 256)];
      As[kk][r] = v;
    }
#pragma unroll
    for (int t = 0; t < 8; ++t) {
      const int i = tid + (t << 8);
      const int kk = i >> 6, c = i & 63;
      Ws[kk][c] = W1[(size_t)(k0 + kk) * NH + ct + c];
    }
    __syncthreads();
#pragma unroll
    for (int kk = 0; kk < 32; ++kk) {
      float a[4], w[4];
#pragma unroll
      for (int r = 0; r < 4; ++r) a[r] = As[kk][ty * 4 + r];
#pragma unroll
      for (int c = 0; c < 4; ++c) w[c] = Ws[kk][tx * 4 + c];
#pragma unroll
      for (int r = 0; r < 4; ++r)
#pragma unroll
        for (int c = 0; c < 4; ++c) acc[r][c] += a[r] * w[c];
    }
    __syncthreads();
  }

#pragma unroll
  for (int r = 0; r < 4; ++r) {
    const int b = b0 + ty * 4 + r;
    const float* ec = nullptr;
    if (embC) {
      const int bit = Lbuf[b * 256 + slotBase + p_local];
      ec = embC + (size_t)bit * NH;
    }
    float* hrow = H + ((size_t)p_local * NB + b) * NH + ct;
#pragma unroll
    for (int c = 0; c < 4; ++c) {
      const int cc = tx * 4 + c;
      float v = acc[r][c] + b1[ct + cc];
      if (embC) v += ec[ct + cc];
      hrow[cc] = fmaxf(v, 0.f);
    }
  }
}

// ---------------- GEMM2: out = hidden @ W2 + b2 ----------------
// rows as g1, K = 512, cols = 256. grid = (CP*4, 4).
__global__ __launch_bounds__(256, 4) void g2_kernel(
    const float* __restrict__ H, float* __restrict__ dst,  // dst = level d+1 base
    const float* __restrict__ W2, const float* __restrict__ b2, int c0)
{
  __shared__ float As[32][68];
  __shared__ float Ws[32][64];
  const int tid = threadIdx.x;
  const int rt = blockIdx.x;
  const int p_local = rt >> 2;
  const int b0 = (rt & 3) << 6;
  const int ct = blockIdx.y << 6;
  const int ty = tid >> 4, tx = tid & 15;
  float acc[4][4] = {{0.f}};
  const float* hbase = H + ((size_t)p_local * NB + b0) * NH;

  for (int k0 = 0; k0 < 512; k0 += 32) {
#pragma unroll
    for (int t = 0; t < 8; ++t) {
      const int i = tid + (t << 8);
      const int r = i >> 5, kk = i & 31;
      As[kk][r] = hbase[(size_t)r * NH + k0 + kk];
    }
#pragma unroll
    for (int t = 0; t < 8; ++t) {
      const int i = tid + (t << 8);
      const int kk = i >> 6, c = i & 63;
      Ws[kk][c] = W2[(size_t)(k0 + kk) * ND + ct + c];
    }
    __syncthreads();
#pragma unroll
    for (int kk = 0; kk < 32; ++kk) {
      float a[4], w[4];
#pragma unroll
      for (int r = 0; r < 4; ++r) a[r] = As[kk][ty * 4 + r];
#pragma unroll
      for (int c = 0; c < 4; ++c) w[c] = Ws[kk][tx * 4 + c];
#pragma unroll
      for (int r = 0; r < 4; ++r)
#pragma unroll
        for (int c = 0; c < 4; ++c) acc[r][c] += a[r] * w[c];
    }
    __syncthreads();
  }

#pragma unroll
  for (int r = 0; r < 4; ++r) {
    const int b = b0 + ty * 4 + r;
    float* orow = dst + ((size_t)(c0 + p_local) * NB + b) * ND + ct;
#pragma unroll
    for (int c = 0; c < 4; ++c) {
      const int cc = tx * 4 + c;
      orow[cc] = acc[r][c] + b2[ct + cc];
    }
  }
}

// ---------------- embC precompute: embC[bit] = label_emb[bit] @ bnW1[512:768] ----------------
__global__ void embc_kernel(const float* __restrict__ lemb,
                            const float* __restrict__ bnW1,
                            float* __restrict__ embC) {
  const int tid = threadIdx.x + blockIdx.x * blockDim.x;  // 1024 total
  const int bitv = tid >> 9, col = tid & 511;
  float s = 0.f;
#pragma unroll 4
  for (int j = 0; j < ND; ++j)
    s += lemb[bitv * ND + j] * bnW1[(size_t)(512 + j) * NH + col];
  embC[bitv * NH + col] = s;
}

// ---------------- leaf: logits, softmax, hard decision, outputs, merge cascade ----------------
__global__ __launch_bounds__(256, 4) void leaf_kernel(
    const float* __restrict__ Ebuf, const float* __restrict__ rv,
    const int* __restrict__ info_set, const int* __restrict__ info_bits,
    const float* __restrict__ llrW, const float* __restrict__ llrb,
    float* __restrict__ out, int* __restrict__ Lbuf, int off)
{
  __shared__ float r0[256], r1[256];
  __shared__ int curS[256], nxtS[256];
  const int tid = threadIdx.x, b = blockIdx.x;
  const float ev = Ebuf[((size_t)254 * NB + b) * ND + tid];  // E level 8, pos 0
  r0[tid] = ev * llrW[2 * tid];
  r1[tid] = ev * llrW[2 * tid + 1];
  __syncthreads();
  for (int s = 128; s > 0; s >>= 1) {
    if (tid < s) { r0[tid] += r0[tid + s]; r1[tid] += r1[tid + s]; }
    __syncthreads();
  }
  if (tid == 0) {
    const float l0 = r0[0] + llrb[0];
    const float l1 = r1[0] + llrb[1];
    const float m = fmaxf(l0, l1);
    const float e0 = expf(l0 - m), e1 = expf(l1 - m);
    const float s = e0 + e1;
    const float p0 = e0 / s, p1 = e1 / s;
    const int hard = (rv[b * NN + off] > p0) ? 1 : 0;
    int lo = 0, hi = NK;
    while (lo < hi) { const int mid = (lo + hi) >> 1; if (info_set[mid] < off) lo = mid + 1; else hi = mid; }
    const int fidx = (lo < NK && info_set[lo] == off) ? lo : -1;
    const int fval = (fidx >= 0) ? info_bits[b * NK + fidx] : 2;
    const int xb = (fval == 2) ? hard : fval;
    out[OUT_F + b * NN + off] = (fidx >= 0) ? 2.0f : (float)xb;
    out[OUT_U + b * NN + off] = (float)xb;
    out[OUT_P + (b * NN + off) * 2 + 0] = p0;
    out[OUT_P + (b * NN + off) * 2 + 1] = p1;
    curS[0] = xb;
  }
  __syncthreads();
  int* cur = curS; int* nxt = nxtS;
  int* Lb = Lbuf + b * 256;
  int len = 1, lev = 8, idx = off;
  while (idx & 1) {
    const int base = loff(lev);
    if (tid < len) {
      const int c = cur[tid];
      nxt[2 * tid] = Lb[base + tid] ^ c;
      nxt[2 * tid + 1] = c;
    }
    __syncthreads();
    int* t = cur; cur = nxt; nxt = t;
    len <<= 1; idx >>= 1; --lev;
  }
  if (lev > 0) {
    if (tid < len) Lb[loff(lev) + tid] = cur[tid];
  } else {
    out[OUT_X + b * NN + tid] = (float)cur[tid];  // off == 255: root codeword
  }
}

extern "C" void kernel_launch(void* const* d_in, const int* in_sizes, int n_in,
                              void* d_out, int out_size, void* d_ws, size_t ws_size,
                              hipStream_t stream) {
  const int*   info_bits = (const int*)d_in[0];
  const float* rv        = (const float*)d_in[1];
  const int*   info_set  = (const int*)d_in[2];
  const float* obs_emb   = (const float*)d_in[3];
  const float* label_emb = (const float*)d_in[4];
  const float* cnW1      = (const float*)d_in[5];
  const float* cnb1      = (const float*)d_in[6];
  const float* cnW2      = (const float*)d_in[7];
  const float* cnb2      = (const float*)d_in[8];
  const float* bnW1      = (const float*)d_in[9];
  const float* bnb1      = (const float*)d_in[10];
  const float* bnW2      = (const float*)d_in[11];
  const float* bnb2      = (const float*)d_in[12];
  const float* llrW      = (const float*)d_in[13];
  const float* llrb      = (const float*)d_in[14];
  const float* obs2      = obs_emb + 2 * ND;

  float* out  = (float*)d_out;
  float* ws   = (float*)d_ws;
  float* Ebuf = ws + E_OFF;
  float* Hbuf = ws + H_OFF;
  float* embC = ws + EC_OFF;
  int*   Lbuf = (int*)((char*)d_ws + L_BYTEOFF);

  embc_kernel<<<dim3(2), dim3(512), 0, stream>>>(label_emb, bnW1, embC);

  auto MLP = [&](int d, bool isBn) {
    const int P = 1 << (7 - d);
    const int CP = P > 32 ? 32 : P;
    const float* src = (d == 0) ? nullptr : Ebuf + (size_t)loff(d) * NB * ND;
    float* dst = Ebuf + (size_t)loff(d + 1) * NB * ND;
    const float* W1 = isBn ? bnW1 : cnW1;
    const float* b1 = isBn ? bnb1 : cnb1;
    const float* W2 = isBn ? bnW2 : cnW2;
    const float* b2 = isBn ? bnb2 : cnb2;
    for (int c0 = 0; c0 < P; c0 += CP) {
      g1_kernel<<<dim3(CP * 4, 8), dim3(256), 0, stream>>>(
          src, Hbuf, W1, b1, isBn ? embC : nullptr, Lbuf, loff(d + 1) + c0, obs2, c0);
      g2_kernel<<<dim3(CP * 4, 4), dim3(256), 0, stream>>>(Hbuf, dst, W2, b2, c0);
    }
  };

  // initial leftmost descent
  for (int d = 0; d < 8; ++d) MLP(d, false);
  // sequential leaves
  for (int off = 0; off < 256; ++off) {
    leaf_kernel<<<dim3(256), dim3(256), 0, stream>>>(
        Ebuf, rv, info_set, info_bits, llrW, llrb, out, Lbuf, off);
    if (off < 255) {
      const int z = __builtin_ctz(off + 1);
      const int dbn = 7 - z;
      MLP(dbn, true);
      for (int d = dbn + 1; d < 8; ++d) MLP(d, false);
    }
  }
}